// Round 5
// baseline (45.782 us; speedup 1.0000x reference)
//
#include <hip/hip_runtime.h>
#include <math.h>

#define T 16
#define A 8
#define H 128
#define E 32
#define G (4*H)   // 512 gate rows per LSTM

typedef _Float16 h2t __attribute__((ext_vector_type(2)));
typedef _Float16 h4t __attribute__((ext_vector_type(4)));
typedef _Float16 h8t __attribute__((ext_vector_type(8)));

__device__ __forceinline__ float sigmoidf_(float x) {
    return 1.0f / (1.0f + __expf(-x));               // safe at both extremes
}
__device__ __forceinline__ float tanhf_(float x) {
    return 1.0f - 2.0f / (1.0f + __expf(2.0f * x));  // safe at both extremes
}

#if __has_builtin(__builtin_amdgcn_fdot2)
#define DOT2(a, b, c) __builtin_amdgcn_fdot2((a), (b), (c), false)
#else
__device__ __forceinline__ float dot2_fb(h2t a, h2t b, float c) {
    return fmaf((float)a[0], (float)b[0], fmaf((float)a[1], (float)b[1], c));
}
#define DOT2(a, b, c) dot2_fb((a), (b), (c))
#endif

#define RPT16(M) M(0) M(1) M(2) M(3) M(4) M(5) M(6) M(7) \
                 M(8) M(9) M(10) M(11) M(12) M(13) M(14) M(15)

__global__ __attribute__((amdgpu_flat_work_group_size(512, 512)))
void ppo_ctrl_kernel(const int* __restrict__ old_actions,
                     const float* __restrict__ init_input,
                     const float* __restrict__ W_ih_a, const float* __restrict__ W_hh_a,
                     const float* __restrict__ b_ih_a, const float* __restrict__ b_hh_a,
                     const float* __restrict__ heads_W, const float* __restrict__ heads_b,
                     const float* __restrict__ W_ih_c, const float* __restrict__ W_hh_c,
                     const float* __restrict__ b_ih_c, const float* __restrict__ b_hh_c,
                     const float* __restrict__ critic_W, const float* __restrict__ critic_b,
                     const float* __restrict__ embed,
                     float* __restrict__ out)
{
    const int tid  = threadIdx.x;
    const int lane = tid & 63;
    const int wv   = tid >> 6;          // 8 waves
    const bool actor = (blockIdx.x == 0);

    const float* W_ih = actor ? W_ih_a : W_ih_c;
    const float* W_hh = actor ? W_hh_a : W_hh_c;
    const float* b_ih = actor ? b_ih_a : b_ih_c;
    const float* b_hh = actor ? b_hh_a : b_hh_c;

    // LDS: 128K weights + 0.25K h + 4K h-history + 2K gates + 2K x = ~136.3 KB
    __shared__ __align__(16) _Float16 wlds[G * H];   // f16, 16B-chunk XOR swizzle
    __shared__ __align__(16) _Float16 h16[H];
    __shared__ __align__(16) _Float16 hhist[T][H];
    __shared__ __align__(16) float gates_s[G];
    __shared__ __align__(16) float x_s[T][E];

    // ---- build x sequence (T*E == 512 == blockDim) ----
    {
        int t0 = tid >> 5, e0 = tid & 31;
        float v = (t0 == 0) ? init_input[e0]
                            : embed[((t0 - 1) * A + old_actions[t0 - 1]) * E + e0];
        x_s[t0][e0] = v;
    }
    if (tid < H) h16[tid] = (_Float16)0.0f;

    // ---- W_hh (f32, coalesced) -> LDS f16, swizzled ----
    // chunk-XOR swizzle: 16B chunk c of row r lives at byte r*256 + ((c*16) ^ ((r&15)*16))
    // => a wave's stride-256B row reads load every bank uniformly (8 words/bank).
    #pragma unroll 4
    for (int pass = 0; pass < 32; ++pass) {
        int idx = pass * 512 + tid;            // float4 index, 16384 total
        float4 f = *(const float4*)(W_hh + idx * 4);
        unsigned r  = (unsigned)idx >> 5;      // row (32 float4 per row)
        unsigned b  = ((unsigned)idx & 31u) * 8u;  // f16 byte offset within row
        unsigned addr = r * 256u + ((b & ~15u) ^ ((r & 15u) * 16u)) + (b & 8u);
        h4t p = { (_Float16)f.x, (_Float16)f.y, (_Float16)f.z, (_Float16)f.w };
        *(h4t*)((char*)wlds + addr) = p;
    }

    // ---- W_ih row (transient, dies after ax computation) + bias ----
    const float* wir = W_ih + tid * E;
    float4 wi0 = *(const float4*)(wir +  0), wi1 = *(const float4*)(wir +  4),
           wi2 = *(const float4*)(wir +  8), wi3 = *(const float4*)(wir + 12),
           wi4 = *(const float4*)(wir + 16), wi5 = *(const float4*)(wir + 20),
           wi6 = *(const float4*)(wir + 24), wi7 = *(const float4*)(wir + 28);
    const float bias = b_ih[tid] + b_hh[tid];

    __syncthreads();   // x_s, h16, wlds ready

    // ---- ax<t> = bias + W_ih[row]@x(t), 16 NAMED scalars ----
#define MACI(tt, i) { float4 xv = *(const float4*)(&x_s[tt][4*(i)]);      \
    s0 = fmaf(wi##i.x, xv.x, s0); s1 = fmaf(wi##i.y, xv.y, s1);           \
    s2 = fmaf(wi##i.z, xv.z, s2); s3 = fmaf(wi##i.w, xv.w, s3); }
#define MAKE_AX(tt) float ax##tt; { float s0=0.f,s1=0.f,s2=0.f,s3=0.f;    \
    MACI(tt,0) MACI(tt,1) MACI(tt,2) MACI(tt,3)                           \
    MACI(tt,4) MACI(tt,5) MACI(tt,6) MACI(tt,7)                           \
    ax##tt = bias + ((s0 + s1) + (s2 + s3)); }
    RPT16(MAKE_AX)
#undef MAKE_AX
#undef MACI

    float c_reg = 0.0f;                       // cell state (threads 0..127)
    const unsigned swzb = ((unsigned)(tid & 15)) * 16u;
    const char* rowbase = (const char*)wlds + tid * 256;
    const char* hbase   = (const char*)h16;

    // ---- 16 steps, fully unrolled; 2 barriers/step; heads deferred ----
#define CHUNK(c) {                                                              \
    h8t wq = *(const h8t*)(rowbase + (((c) * 16u) ^ swzb));                     \
    h8t hq = *(const h8t*)(hbase + (c) * 16);                                   \
    a0 = DOT2(__builtin_shufflevector(wq,wq,0,1), __builtin_shufflevector(hq,hq,0,1), a0); \
    a1 = DOT2(__builtin_shufflevector(wq,wq,2,3), __builtin_shufflevector(hq,hq,2,3), a1); \
    a2 = DOT2(__builtin_shufflevector(wq,wq,4,5), __builtin_shufflevector(hq,hq,4,5), a2); \
    a3 = DOT2(__builtin_shufflevector(wq,wq,6,7), __builtin_shufflevector(hq,hq,6,7), a3); }

#define STEP(tt) {                                                        \
    float a0=0.f, a1=0.f, a2=0.f, a3=0.f;                                 \
    CHUNK(0)  CHUNK(1)  CHUNK(2)  CHUNK(3)                                \
    CHUNK(4)  CHUNK(5)  CHUNK(6)  CHUNK(7)                                \
    CHUNK(8)  CHUNK(9)  CHUNK(10) CHUNK(11)                               \
    CHUNK(12) CHUNK(13) CHUNK(14) CHUNK(15)                               \
    gates_s[tid] = ax##tt + ((a0 + a1) + (a2 + a3));                      \
    __syncthreads();                                                      \
    if (tid < H) {                                                        \
        float gi = gates_s[tid],       gf = gates_s[tid + H];             \
        float gg = gates_s[tid + 2*H], go = gates_s[tid + 3*H];           \
        float cn = sigmoidf_(gf) * c_reg + sigmoidf_(gi) * tanhf_(gg);    \
        c_reg = cn;                                                       \
        float hv = sigmoidf_(go) * tanhf_(cn);                            \
        _Float16 hf = (_Float16)hv;                                       \
        h16[tid] = hf; hhist[tt][tid] = hf;                               \
    }                                                                     \
    __syncthreads(); }

    RPT16(STEP)
#undef STEP
#undef CHUNK

    // ---- heads: all 16 steps in parallel (off the serial path) ----
    if (actor) {
        #pragma unroll 1
        for (int tt = wv; tt < T; tt += 8) {       // wave wv -> t = wv, wv+8
            float hA = (float)hhist[tt][lane];
            float hB = (float)hhist[tt][64 + lane];
#define LOGIT(a) float l##a; {                                            \
            const float* hw = heads_W + ((tt) * A + (a)) * H;             \
            float p = fmaf(hw[lane], hA, hw[64 + lane] * hB);             \
            p += __shfl_xor(p, 1);  p += __shfl_xor(p, 2);                \
            p += __shfl_xor(p, 4);  p += __shfl_xor(p, 8);                \
            p += __shfl_xor(p, 16); p += __shfl_xor(p, 32);               \
            l##a = p + heads_b[(tt) * A + (a)]; }
            LOGIT(0) LOGIT(1) LOGIT(2) LOGIT(3)
            LOGIT(4) LOGIT(5) LOGIT(6) LOGIT(7)
#undef LOGIT
            if (lane == 0) {
                float m = fmaxf(fmaxf(fmaxf(l0, l1), fmaxf(l2, l3)),
                                fmaxf(fmaxf(l4, l5), fmaxf(l6, l7)));
                float e0 = __expf(l0 - m), e1 = __expf(l1 - m),
                      e2 = __expf(l2 - m), e3 = __expf(l3 - m),
                      e4 = __expf(l4 - m), e5 = __expf(l5 - m),
                      e6 = __expf(l6 - m), e7 = __expf(l7 - m);
                float s = ((e0 + e1) + (e2 + e3)) + ((e4 + e5) + (e6 + e7));
                float logZ = m + __logf(s);
                int act = old_actions[tt];
                float la = (act == 0) ? l0 : (act == 1) ? l1 : (act == 2) ? l2 :
                           (act == 3) ? l3 : (act == 4) ? l4 : (act == 5) ? l5 :
                           (act == 6) ? l6 : l7;
                out[tt] = la - logZ;                       // log_probs
                float w_ = e0*(l0-logZ) + e1*(l1-logZ) + e2*(l2-logZ) + e3*(l3-logZ)
                         + e4*(l4-logZ) + e5*(l5-logZ) + e6*(l6-logZ) + e7*(l7-logZ);
                out[T + tt] = -w_ / s;                     // entropies
            }
        }
    } else {
        #pragma unroll 1
        for (int tt = wv; tt < T; tt += 8) {
            float hA = (float)hhist[tt][lane];
            float hB = (float)hhist[tt][64 + lane];
            float p = fmaf(critic_W[lane], hA, critic_W[64 + lane] * hB);
            p += __shfl_xor(p, 1);  p += __shfl_xor(p, 2);
            p += __shfl_xor(p, 4);  p += __shfl_xor(p, 8);
            p += __shfl_xor(p, 16); p += __shfl_xor(p, 32);
            if (lane == 0) out[2 * T + tt] = p + critic_b[0];   // values
        }
    }
}

extern "C" void kernel_launch(void* const* d_in, const int* in_sizes, int n_in,
                              void* d_out, int out_size, void* d_ws, size_t ws_size,
                              hipStream_t stream) {
    const int*   old_actions = (const int*)  d_in[0];
    const float* init_input  = (const float*)d_in[1];
    const float* W_ih_a      = (const float*)d_in[2];
    const float* W_hh_a      = (const float*)d_in[3];
    const float* b_ih_a      = (const float*)d_in[4];
    const float* b_hh_a      = (const float*)d_in[5];
    const float* heads_W     = (const float*)d_in[6];
    const float* heads_b     = (const float*)d_in[7];
    const float* W_ih_c      = (const float*)d_in[8];
    const float* W_hh_c      = (const float*)d_in[9];
    const float* b_ih_c      = (const float*)d_in[10];
    const float* b_hh_c      = (const float*)d_in[11];
    const float* critic_W    = (const float*)d_in[12];
    const float* critic_b    = (const float*)d_in[13];
    const float* embed       = (const float*)d_in[14];
    float* out = (float*)d_out;

    ppo_ctrl_kernel<<<dim3(2), dim3(512), 0, stream>>>(
        old_actions, init_input,
        W_ih_a, W_hh_a, b_ih_a, b_hh_a,
        heads_W, heads_b,
        W_ih_c, W_hh_c, b_ih_c, b_hh_c,
        critic_W, critic_b, embed, out);
}

// Round 6
// 29.092 us; speedup vs baseline: 1.5737x; 1.5737x over previous
//
#include <hip/hip_runtime.h>
#include <math.h>

#define T 16
#define A 8
#define H 128
#define E 32
#define G (4*H)   // 512 gate rows per LSTM

typedef _Float16 h2t __attribute__((ext_vector_type(2)));
typedef _Float16 h4t __attribute__((ext_vector_type(4)));
typedef _Float16 h8t __attribute__((ext_vector_type(8)));

__device__ __forceinline__ float sigmoidf_(float x) {
    return 1.0f / (1.0f + __expf(-x));               // safe at both extremes
}
__device__ __forceinline__ float tanhf_(float x) {
    return 1.0f - 2.0f / (1.0f + __expf(2.0f * x));  // safe at both extremes
}

#if __has_builtin(__builtin_amdgcn_fdot2)
#define DOT2(a, b, c) __builtin_amdgcn_fdot2((a), (b), (c), false)
#else
__device__ __forceinline__ float dot2_fb(h2t a, h2t b, float c) {
    return fmaf((float)a[0], (float)b[0], fmaf((float)a[1], (float)b[1], c));
}
#define DOT2(a, b, c) dot2_fb((a), (b), (c))
#endif

// waves_per_eu(2,2): exact 2 waves/SIMD -> 256-VGPR budget. Round 5 omitted
// this and the unrolled body spilled (WRITE_SIZE 0.2KB -> 768KB, dur up).
__global__ __attribute__((amdgpu_flat_work_group_size(512, 512),
                          amdgpu_waves_per_eu(2, 2)))
void ppo_ctrl_kernel(const int* __restrict__ old_actions,
                     const float* __restrict__ init_input,
                     const float* __restrict__ W_ih_a, const float* __restrict__ W_hh_a,
                     const float* __restrict__ b_ih_a, const float* __restrict__ b_hh_a,
                     const float* __restrict__ heads_W, const float* __restrict__ heads_b,
                     const float* __restrict__ W_ih_c, const float* __restrict__ W_hh_c,
                     const float* __restrict__ b_ih_c, const float* __restrict__ b_hh_c,
                     const float* __restrict__ critic_W, const float* __restrict__ critic_b,
                     const float* __restrict__ embed,
                     float* __restrict__ out)
{
    const int tid  = threadIdx.x;
    const int lane = tid & 63;
    const int wv   = tid >> 6;          // 8 waves
    const bool actor = (blockIdx.x == 0);

    const float* W_ih = actor ? W_ih_a : W_ih_c;
    const float* W_hh = actor ? W_hh_a : W_hh_c;
    const float* b_ih = actor ? b_ih_a : b_ih_c;
    const float* b_hh = actor ? b_hh_a : b_hh_c;

    // LDS budget: 128K + 16K + 4K + 2K + 2K + 0.25K = 152.25 KiB (< 160 KiB)
    __shared__ __align__(16) _Float16 wlds[G * H];     // f16 weights, XOR-swizzled
    __shared__ __align__(16) _Float16 accx16[T][G];    // bias + W_ih@x(t) per row
    __shared__ __align__(16) _Float16 hhist[T][H];
    __shared__ __align__(16) float gates_s[G];
    __shared__ __align__(16) float x_s[T][E];
    __shared__ __align__(16) _Float16 h16[H];

    // ---- build x sequence (T*E == 512 == blockDim) ----
    {
        int t0 = tid >> 5, e0 = tid & 31;
        float v = (t0 == 0) ? init_input[e0]
                            : embed[((t0 - 1) * A + old_actions[t0 - 1]) * E + e0];
        x_s[t0][e0] = v;
    }
    if (tid < H) h16[tid] = (_Float16)0.0f;

    // ---- W_hh (f32 global, coalesced) -> LDS f16, 16B-chunk XOR swizzle ----
    // chunk c of row r lives at byte r*256 + ((c*16) ^ ((r&15)*16)); a wave's
    // stride-256B row reads then hit every bank uniformly (8 words/bank/b128).
    #pragma unroll 4
    for (int pass = 0; pass < 32; ++pass) {
        int idx = pass * 512 + tid;                // float4 index, 16384 total
        float4 f = *(const float4*)(W_hh + idx * 4);
        unsigned r = (unsigned)idx >> 5;           // row (32 float4 per row)
        unsigned b = ((unsigned)idx & 31u) * 8u;   // f16 byte offset within row
        unsigned addr = r * 256u + ((b & ~15u) ^ ((r & 15u) * 16u)) + (b & 8u);
        h4t p = { (_Float16)f.x, (_Float16)f.y, (_Float16)f.z, (_Float16)f.w };
        *(h4t*)((char*)wlds + addr) = p;
    }

    // ---- W_ih row (transient) + bias ----
    const float* wir = W_ih + tid * E;
    float4 wi0 = *(const float4*)(wir +  0), wi1 = *(const float4*)(wir +  4),
           wi2 = *(const float4*)(wir +  8), wi3 = *(const float4*)(wir + 12),
           wi4 = *(const float4*)(wir + 16), wi5 = *(const float4*)(wir + 20),
           wi6 = *(const float4*)(wir + 24), wi7 = *(const float4*)(wir + 28);
    const float bias = b_ih[tid] + b_hh[tid];

    __syncthreads();   // x_s, h16, wlds ready

    // ---- accx16[t][row] = bias + W_ih[row]@x(t) (same-thread r/w, no barrier) ----
    #pragma unroll 1
    for (int t = 0; t < T; ++t) {
        float s0 = 0.f, s1 = 0.f, s2 = 0.f, s3 = 0.f;
#define MACI(i) { float4 xv = *(const float4*)(&x_s[t][4*(i)]);           \
        s0 = fmaf(wi##i.x, xv.x, s0); s1 = fmaf(wi##i.y, xv.y, s1);       \
        s2 = fmaf(wi##i.z, xv.z, s2); s3 = fmaf(wi##i.w, xv.w, s3); }
        MACI(0) MACI(1) MACI(2) MACI(3) MACI(4) MACI(5) MACI(6) MACI(7)
#undef MACI
        accx16[t][tid] = (_Float16)(bias + ((s0 + s1) + (s2 + s3)));
    }

    float c_reg = 0.0f;                         // cell state (threads 0..127)
    const unsigned swzb = ((unsigned)(tid & 15)) * 16u;
    const char* rowbase = (const char*)wlds + tid * 256;
    const char* hbase   = (const char*)h16;

    // ---- 16 sequential steps, NOT unrolled (tiny body, ~10 live regs) ----
    #pragma unroll 1
    for (int t = 0; t < T; ++t) {
        float a0 = 0.f, a1 = 0.f, a2 = 0.f, a3 = 0.f;
        #pragma unroll
        for (int c = 0; c < 16; ++c) {
            h8t wq = *(const h8t*)(rowbase + (((unsigned)c * 16u) ^ swzb));
            h8t hq = *(const h8t*)(hbase + c * 16);   // broadcast: conflict-free
            a0 = DOT2(__builtin_shufflevector(wq, wq, 0, 1),
                      __builtin_shufflevector(hq, hq, 0, 1), a0);
            a1 = DOT2(__builtin_shufflevector(wq, wq, 2, 3),
                      __builtin_shufflevector(hq, hq, 2, 3), a1);
            a2 = DOT2(__builtin_shufflevector(wq, wq, 4, 5),
                      __builtin_shufflevector(hq, hq, 4, 5), a2);
            a3 = DOT2(__builtin_shufflevector(wq, wq, 6, 7),
                      __builtin_shufflevector(hq, hq, 6, 7), a3);
        }
        gates_s[tid] = (float)accx16[t][tid] + ((a0 + a1) + (a2 + a3));
        __syncthreads();

        if (tid < H) {   // gate order i,f,g,o
            float gi = gates_s[tid],       gf = gates_s[tid + H];
            float gg = gates_s[tid + 2*H], go = gates_s[tid + 3*H];
            float cn = sigmoidf_(gf) * c_reg + sigmoidf_(gi) * tanhf_(gg);
            c_reg = cn;
            float hv = sigmoidf_(go) * tanhf_(cn);
            _Float16 hf = (_Float16)hv;
            h16[tid] = hf;
            hhist[t][tid] = hf;
        }
        __syncthreads();
    }

    // ---- heads: all 16 steps in parallel (off the serial path) ----
    if (actor) {
        #pragma unroll 1
        for (int tt = wv; tt < T; tt += 8) {       // wave wv -> t = wv, wv+8
            float hA = (float)hhist[tt][lane];
            float hB = (float)hhist[tt][64 + lane];
#define LOGIT(a) float l##a; {                                            \
            const float* hw = heads_W + ((tt) * A + (a)) * H;             \
            float p = fmaf(hw[lane], hA, hw[64 + lane] * hB);             \
            p += __shfl_xor(p, 1);  p += __shfl_xor(p, 2);                \
            p += __shfl_xor(p, 4);  p += __shfl_xor(p, 8);                \
            p += __shfl_xor(p, 16); p += __shfl_xor(p, 32);               \
            l##a = p + heads_b[(tt) * A + (a)]; }
            LOGIT(0) LOGIT(1) LOGIT(2) LOGIT(3)
            LOGIT(4) LOGIT(5) LOGIT(6) LOGIT(7)
#undef LOGIT
            if (lane == 0) {
                float m = fmaxf(fmaxf(fmaxf(l0, l1), fmaxf(l2, l3)),
                                fmaxf(fmaxf(l4, l5), fmaxf(l6, l7)));
                float e0 = __expf(l0 - m), e1 = __expf(l1 - m),
                      e2 = __expf(l2 - m), e3 = __expf(l3 - m),
                      e4 = __expf(l4 - m), e5 = __expf(l5 - m),
                      e6 = __expf(l6 - m), e7 = __expf(l7 - m);
                float s = ((e0 + e1) + (e2 + e3)) + ((e4 + e5) + (e6 + e7));
                float logZ = m + __logf(s);
                int act = old_actions[tt];
                float la = (act == 0) ? l0 : (act == 1) ? l1 : (act == 2) ? l2 :
                           (act == 3) ? l3 : (act == 4) ? l4 : (act == 5) ? l5 :
                           (act == 6) ? l6 : l7;
                out[tt] = la - logZ;                       // log_probs
                float w_ = e0*(l0-logZ) + e1*(l1-logZ) + e2*(l2-logZ) + e3*(l3-logZ)
                         + e4*(l4-logZ) + e5*(l5-logZ) + e6*(l6-logZ) + e7*(l7-logZ);
                out[T + tt] = -w_ / s;                     // entropies
            }
        }
    } else {
        #pragma unroll 1
        for (int tt = wv; tt < T; tt += 8) {
            float hA = (float)hhist[tt][lane];
            float hB = (float)hhist[tt][64 + lane];
            float p = fmaf(critic_W[lane], hA, critic_W[64 + lane] * hB);
            p += __shfl_xor(p, 1);  p += __shfl_xor(p, 2);
            p += __shfl_xor(p, 4);  p += __shfl_xor(p, 8);
            p += __shfl_xor(p, 16); p += __shfl_xor(p, 32);
            if (lane == 0) out[2 * T + tt] = p + critic_b[0];   // values
        }
    }
}

extern "C" void kernel_launch(void* const* d_in, const int* in_sizes, int n_in,
                              void* d_out, int out_size, void* d_ws, size_t ws_size,
                              hipStream_t stream) {
    const int*   old_actions = (const int*)  d_in[0];
    const float* init_input  = (const float*)d_in[1];
    const float* W_ih_a      = (const float*)d_in[2];
    const float* W_hh_a      = (const float*)d_in[3];
    const float* b_ih_a      = (const float*)d_in[4];
    const float* b_hh_a      = (const float*)d_in[5];
    const float* heads_W     = (const float*)d_in[6];
    const float* heads_b     = (const float*)d_in[7];
    const float* W_ih_c      = (const float*)d_in[8];
    const float* W_hh_c      = (const float*)d_in[9];
    const float* b_ih_c      = (const float*)d_in[10];
    const float* b_hh_c      = (const float*)d_in[11];
    const float* critic_W    = (const float*)d_in[12];
    const float* critic_b    = (const float*)d_in[13];
    const float* embed       = (const float*)d_in[14];
    float* out = (float*)d_out;

    ppo_ctrl_kernel<<<dim3(2), dim3(512), 0, stream>>>(
        old_actions, init_input,
        W_ih_a, W_hh_a, b_ih_a, b_hh_a,
        heads_W, heads_b,
        W_ih_c, W_hh_c, b_ih_c, b_hh_c,
        critic_W, critic_b, embed, out);
}

// Round 7
// 28.969 us; speedup vs baseline: 1.5804x; 1.0042x over previous
//
#include <hip/hip_runtime.h>
#include <math.h>

#define T 16
#define A 8
#define H 128
#define E 32
#define G (4*H)   // 512 gate rows per LSTM

typedef _Float16 h2t __attribute__((ext_vector_type(2)));
typedef _Float16 h4t __attribute__((ext_vector_type(4)));
typedef _Float16 h8t __attribute__((ext_vector_type(8)));

__device__ __forceinline__ float sigmoidf_(float x) {
    return 1.0f / (1.0f + __expf(-x));               // safe at both extremes
}
__device__ __forceinline__ float tanhf_(float x) {
    return 1.0f - 2.0f / (1.0f + __expf(2.0f * x));  // safe at both extremes
}

#if __has_builtin(__builtin_amdgcn_fdot2)
#define DOT2(a, b, c) __builtin_amdgcn_fdot2((a), (b), (c), false)
#else
__device__ __forceinline__ float dot2_fb(h2t a, h2t b, float c) {
    return fmaf((float)a[0], (float)b[0], fmaf((float)a[1], (float)b[1], c));
}
#define DOT2(a, b, c) dot2_fb((a), (b), (c))
#endif

// waves_per_eu(2,2): exact 2 waves/SIMD -> 256-VGPR budget. Round 5 omitted
// this and the unrolled body spilled (WRITE_SIZE 0.2KB -> 768KB, dur up).
__global__ __attribute__((amdgpu_flat_work_group_size(512, 512),
                          amdgpu_waves_per_eu(2, 2)))
void ppo_ctrl_kernel(const int* __restrict__ old_actions,
                     const float* __restrict__ init_input,
                     const float* __restrict__ W_ih_a, const float* __restrict__ W_hh_a,
                     const float* __restrict__ b_ih_a, const float* __restrict__ b_hh_a,
                     const float* __restrict__ heads_W, const float* __restrict__ heads_b,
                     const float* __restrict__ W_ih_c, const float* __restrict__ W_hh_c,
                     const float* __restrict__ b_ih_c, const float* __restrict__ b_hh_c,
                     const float* __restrict__ critic_W, const float* __restrict__ critic_b,
                     const float* __restrict__ embed,
                     float* __restrict__ out)
{
    const int tid  = threadIdx.x;
    const int lane = tid & 63;
    const int wv   = tid >> 6;          // 8 waves
    const bool actor = (blockIdx.x == 0);

    const float* W_ih = actor ? W_ih_a : W_ih_c;
    const float* W_hh = actor ? W_hh_a : W_hh_c;
    const float* b_ih = actor ? b_ih_a : b_ih_c;
    const float* b_hh = actor ? b_hh_a : b_hh_c;

    // LDS budget: 128K + 16K + 4K + 2K + 2K + 0.25K = 152.25 KiB (< 160 KiB)
    __shared__ __align__(16) _Float16 wlds[G * H];     // f16 weights, XOR-swizzled
    __shared__ __align__(16) _Float16 accx16[T][G];    // bias + W_ih@x(t) per row
    __shared__ __align__(16) _Float16 hhist[T][H];
    __shared__ __align__(16) float gates_s[G];
    __shared__ __align__(16) float x_s[T][E];
    __shared__ __align__(16) _Float16 h16[H];

    // ---- build x sequence (T*E == 512 == blockDim) ----
    {
        int t0 = tid >> 5, e0 = tid & 31;
        float v = (t0 == 0) ? init_input[e0]
                            : embed[((t0 - 1) * A + old_actions[t0 - 1]) * E + e0];
        x_s[t0][e0] = v;
    }
    if (tid < H) h16[tid] = (_Float16)0.0f;

    // ---- W_hh (f32 global, coalesced) -> LDS f16, 16B-chunk XOR swizzle ----
    // chunk c of row r lives at byte r*256 + ((c*16) ^ ((r&15)*16)); a wave's
    // stride-256B row reads then hit every bank uniformly (8 words/bank/b128).
    #pragma unroll 4
    for (int pass = 0; pass < 32; ++pass) {
        int idx = pass * 512 + tid;                // float4 index, 16384 total
        float4 f = *(const float4*)(W_hh + idx * 4);
        unsigned r = (unsigned)idx >> 5;           // row (32 float4 per row)
        unsigned b = ((unsigned)idx & 31u) * 8u;   // f16 byte offset within row
        unsigned addr = r * 256u + ((b & ~15u) ^ ((r & 15u) * 16u)) + (b & 8u);
        h4t p = { (_Float16)f.x, (_Float16)f.y, (_Float16)f.z, (_Float16)f.w };
        *(h4t*)((char*)wlds + addr) = p;
    }

    // ---- W_ih row (transient) + bias ----
    const float* wir = W_ih + tid * E;
    float4 wi0 = *(const float4*)(wir +  0), wi1 = *(const float4*)(wir +  4),
           wi2 = *(const float4*)(wir +  8), wi3 = *(const float4*)(wir + 12),
           wi4 = *(const float4*)(wir + 16), wi5 = *(const float4*)(wir + 20),
           wi6 = *(const float4*)(wir + 24), wi7 = *(const float4*)(wir + 28);
    const float bias = b_ih[tid] + b_hh[tid];

    __syncthreads();   // x_s, h16, wlds ready

    // ---- accx16[t][row] = bias + W_ih[row]@x(t) (same-thread r/w, no barrier) ----
    #pragma unroll 1
    for (int t = 0; t < T; ++t) {
        float s0 = 0.f, s1 = 0.f, s2 = 0.f, s3 = 0.f;
#define MACI(i) { float4 xv = *(const float4*)(&x_s[t][4*(i)]);           \
        s0 = fmaf(wi##i.x, xv.x, s0); s1 = fmaf(wi##i.y, xv.y, s1);       \
        s2 = fmaf(wi##i.z, xv.z, s2); s3 = fmaf(wi##i.w, xv.w, s3); }
        MACI(0) MACI(1) MACI(2) MACI(3) MACI(4) MACI(5) MACI(6) MACI(7)
#undef MACI
        accx16[t][tid] = (_Float16)(bias + ((s0 + s1) + (s2 + s3)));
    }

    float c_reg = 0.0f;                         // cell state (threads 0..127)
    const unsigned swzb = ((unsigned)(tid & 15)) * 16u;
    const char* rowbase = (const char*)wlds + tid * 256;
    const char* hbase   = (const char*)h16;

    // ---- 16 sequential steps, NOT unrolled (tiny body, ~10 live regs) ----
    #pragma unroll 1
    for (int t = 0; t < T; ++t) {
        float a0 = 0.f, a1 = 0.f, a2 = 0.f, a3 = 0.f;
        #pragma unroll
        for (int c = 0; c < 16; ++c) {
            h8t wq = *(const h8t*)(rowbase + (((unsigned)c * 16u) ^ swzb));
            h8t hq = *(const h8t*)(hbase + c * 16);   // broadcast: conflict-free
            a0 = DOT2(__builtin_shufflevector(wq, wq, 0, 1),
                      __builtin_shufflevector(hq, hq, 0, 1), a0);
            a1 = DOT2(__builtin_shufflevector(wq, wq, 2, 3),
                      __builtin_shufflevector(hq, hq, 2, 3), a1);
            a2 = DOT2(__builtin_shufflevector(wq, wq, 4, 5),
                      __builtin_shufflevector(hq, hq, 4, 5), a2);
            a3 = DOT2(__builtin_shufflevector(wq, wq, 6, 7),
                      __builtin_shufflevector(hq, hq, 6, 7), a3);
        }
        gates_s[tid] = (float)accx16[t][tid] + ((a0 + a1) + (a2 + a3));
        __syncthreads();

        if (tid < H) {   // gate order i,f,g,o
            float gi = gates_s[tid],       gf = gates_s[tid + H];
            float gg = gates_s[tid + 2*H], go = gates_s[tid + 3*H];
            float cn = sigmoidf_(gf) * c_reg + sigmoidf_(gi) * tanhf_(gg);
            c_reg = cn;
            float hv = sigmoidf_(go) * tanhf_(cn);
            _Float16 hf = (_Float16)hv;
            h16[tid] = hf;
            hhist[t][tid] = hf;
        }
        __syncthreads();
    }

    // ---- heads: all 16 steps in parallel (off the serial path) ----
    if (actor) {
        #pragma unroll 1
        for (int tt = wv; tt < T; tt += 8) {       // wave wv -> t = wv, wv+8
            float hA = (float)hhist[tt][lane];
            float hB = (float)hhist[tt][64 + lane];
#define LOGIT(a) float l##a; {                                            \
            const float* hw = heads_W + ((tt) * A + (a)) * H;             \
            float p = fmaf(hw[lane], hA, hw[64 + lane] * hB);             \
            p += __shfl_xor(p, 1);  p += __shfl_xor(p, 2);                \
            p += __shfl_xor(p, 4);  p += __shfl_xor(p, 8);                \
            p += __shfl_xor(p, 16); p += __shfl_xor(p, 32);               \
            l##a = p + heads_b[(tt) * A + (a)]; }
            LOGIT(0) LOGIT(1) LOGIT(2) LOGIT(3)
            LOGIT(4) LOGIT(5) LOGIT(6) LOGIT(7)
#undef LOGIT
            if (lane == 0) {
                float m = fmaxf(fmaxf(fmaxf(l0, l1), fmaxf(l2, l3)),
                                fmaxf(fmaxf(l4, l5), fmaxf(l6, l7)));
                float e0 = __expf(l0 - m), e1 = __expf(l1 - m),
                      e2 = __expf(l2 - m), e3 = __expf(l3 - m),
                      e4 = __expf(l4 - m), e5 = __expf(l5 - m),
                      e6 = __expf(l6 - m), e7 = __expf(l7 - m);
                float s = ((e0 + e1) + (e2 + e3)) + ((e4 + e5) + (e6 + e7));
                float logZ = m + __logf(s);
                int act = old_actions[tt];
                float la = (act == 0) ? l0 : (act == 1) ? l1 : (act == 2) ? l2 :
                           (act == 3) ? l3 : (act == 4) ? l4 : (act == 5) ? l5 :
                           (act == 6) ? l6 : l7;
                out[tt] = la - logZ;                       // log_probs
                float w_ = e0*(l0-logZ) + e1*(l1-logZ) + e2*(l2-logZ) + e3*(l3-logZ)
                         + e4*(l4-logZ) + e5*(l5-logZ) + e6*(l6-logZ) + e7*(l7-logZ);
                out[T + tt] = -w_ / s;                     // entropies
            }
        }
    } else {
        #pragma unroll 1
        for (int tt = wv; tt < T; tt += 8) {
            float hA = (float)hhist[tt][lane];
            float hB = (float)hhist[tt][64 + lane];
            float p = fmaf(critic_W[lane], hA, critic_W[64 + lane] * hB);
            p += __shfl_xor(p, 1);  p += __shfl_xor(p, 2);
            p += __shfl_xor(p, 4);  p += __shfl_xor(p, 8);
            p += __shfl_xor(p, 16); p += __shfl_xor(p, 32);
            if (lane == 0) out[2 * T + tt] = p + critic_b[0];   // values
        }
    }
}

extern "C" void kernel_launch(void* const* d_in, const int* in_sizes, int n_in,
                              void* d_out, int out_size, void* d_ws, size_t ws_size,
                              hipStream_t stream) {
    const int*   old_actions = (const int*)  d_in[0];
    const float* init_input  = (const float*)d_in[1];
    const float* W_ih_a      = (const float*)d_in[2];
    const float* W_hh_a      = (const float*)d_in[3];
    const float* b_ih_a      = (const float*)d_in[4];
    const float* b_hh_a      = (const float*)d_in[5];
    const float* heads_W     = (const float*)d_in[6];
    const float* heads_b     = (const float*)d_in[7];
    const float* W_ih_c      = (const float*)d_in[8];
    const float* W_hh_c      = (const float*)d_in[9];
    const float* b_ih_c      = (const float*)d_in[10];
    const float* b_hh_c      = (const float*)d_in[11];
    const float* critic_W    = (const float*)d_in[12];
    const float* critic_b    = (const float*)d_in[13];
    const float* embed       = (const float*)d_in[14];
    float* out = (float*)d_out;

    ppo_ctrl_kernel<<<dim3(2), dim3(512), 0, stream>>>(
        old_actions, init_input,
        W_ih_a, W_hh_a, b_ih_a, b_hh_a,
        heads_W, heads_b,
        W_ih_c, W_hh_c, b_ih_c, b_hh_c,
        critic_W, critic_b, embed, out);
}